// Round 13
// baseline (201.089 us; speedup 1.0000x reference)
//
#include <hip/hip_runtime.h>

#define B_ 128
#define T_ 256
#define C_ 512
#define H_ 512
// softmax scale * log2(e):  (1/sqrt(512)) * 1.44269504
#define CSCALE 0.063763824f

typedef _Float16 f16x8 __attribute__((ext_vector_type(8)));
typedef _Float16 f16x4 __attribute__((ext_vector_type(4)));
typedef _Float16 f16x2 __attribute__((ext_vector_type(2)));
typedef float    f32x4 __attribute__((ext_vector_type(4)));
typedef float    f32x16 __attribute__((ext_vector_type(16)));
typedef unsigned int u32;
typedef u32 u32x4 __attribute__((ext_vector_type(4)));

// async global->LDS, 16B per lane; LDS dest must be wave-uniform base (+lane*16)
__device__ __forceinline__ void gld16(const void* gsrc, void* ldst) {
  __builtin_amdgcn_global_load_lds(
      (__attribute__((address_space(1))) void*)gsrc,
      (__attribute__((address_space(3))) void*)ldst, 16, 0, 0);
}

// ---------------------------------------------------------------- x convert
__global__ __launch_bounds__(256) void cvtx_kernel(
    const float4* __restrict__ x, f16x4* __restrict__ dst) {
  const int NX = (B_ * T_ * C_) / 4;  // 4,194,304
  int gid = blockIdx.x * 256 + threadIdx.x;
  int gsz = gridDim.x * 256;
  for (int i = gid; i < NX; i += gsz) {
    float4 f = x[i];
    f16x4 u = {(_Float16)f.x, (_Float16)f.y, (_Float16)f.z, (_Float16)f.w};
    dst[i] = u;
  }
}

// ---------------------------------------------------------------- W convert
__global__ __launch_bounds__(256) void cvtw_kernel(
    const float4* __restrict__ wq, const float4* __restrict__ wk,
    const float4* __restrict__ wv, f16x4* __restrict__ dst) {
  const int NW = (H_ * C_) / 4;  // 65,536
  int i = blockIdx.x * 256 + threadIdx.x;
  if (i >= 3 * NW) return;
  float4 f = (i < NW) ? wq[i] : (i < 2 * NW ? wk[i - NW] : wv[i - 2 * NW]);
  f16x4 u = {(_Float16)f.x, (_Float16)f.y, (_Float16)f.z, (_Float16)f.w};
  dst[i] = u;
}

// ---------------------------------------------------------------- QKV proj
// R5 2-barrier skeleton + two drain-reduction mechanisms:
// (1) XCD temporal locality: flat = xcd + 8*(inner + 12*outer); the 12
//     (n,z) blocks sharing an A-panel run consecutively on ONE XCD ->
//     concurrent L2 working set ~4 MB (was 5.5 scattered) -> A drains at
//     L2 latency, not L3/HBM.
// (2) BK=64: 8 vmcnt(0) drains per block instead of 16 (drain exposure
//     halves); 32 MFMA per step per wave. LDS 32 KB -> 5 blocks/CU.
// Conflict-free group layout: group = 16 rows x 32 cols (1 KB), slot =
// reader lane (gld16 sources pre-permuted, G21 both-sides).
__global__ __launch_bounds__(256) void proj_kernel(
    const _Float16* __restrict__ xh, const _Float16* __restrict__ wh,
    _Float16* __restrict__ qh, _Float16* __restrict__ kh,
    _Float16* __restrict__ vth) {
  __shared__ _Float16 As[16][512];  // 16 KB: [rowgroup*2 + kk][slot]
  __shared__ _Float16 Bs[16][512];  // 16 KB

  const int tid  = threadIdx.x;
  const int lane = tid & 63;
  const int wave = tid >> 6;          // 0..3
  const int lr = lane & 15, lk = lane >> 4;
  const int lane8 = lane * 8;

  // XCD-pinned, panel-sharing-consecutive decomposition (bijective, 3072=8*12*32)
  const int flat  = blockIdx.x;
  const int xcd   = flat & 7;
  const int r     = flat >> 3;        // 0..383
  const int inner = r % 12;           // 12 (n,z) variants, consecutive per chunk
  const int outer = r / 12;           // 32 m-chunks per XCD
  const int m0 = (xcd + 8 * outer) * 128;
  const int n0 = (inner & 3) * 128;
  const int z  = inner >> 2;
  const _Float16* wz = wh + z * (H_ * C_);

  const int wm = (wave >> 1) * 64;
  const int wn = (wave & 1) * 64;
  const int ga = (wave >> 1) * 4;     // A rowgroup base for reads
  const int gb = (wave & 1) * 4;      // B rowgroup base for reads

  f32x4 acc[4][4];
#pragma unroll
  for (int i = 0; i < 4; ++i)
#pragma unroll
    for (int j = 0; j < 4; ++j) acc[i][j] = {0.f, 0.f, 0.f, 0.f};

  // stage sources: group (rg, kk): row = base + rg*16 + (l&15),
  // col = k0 + kk*32 + (l>>4)*8  -- matches gld16 linear lane*16B dest
  const _Float16* aS = xh + (size_t)(m0 + wave * 16 + lr) * C_ + lk * 8;
  const _Float16* bS = wz + (size_t)(n0 + wave * 16 + lr) * C_ + lk * 8;

#pragma unroll 1
  for (int t = 0; t < 8; ++t) {
    const int k0 = t * 64;
    __syncthreads();  // previous compute done reading LDS
    // wave writes A rowgroups {wave, wave+4} x kk{0,1}; same for B
    gld16((const void*)(aS + k0),                 (void*)&As[wave * 2][0]);
    gld16((const void*)(aS + k0 + 32),            (void*)&As[wave * 2 + 1][0]);
    gld16((const void*)(aS + 64 * C_ + k0),       (void*)&As[(wave + 4) * 2][0]);
    gld16((const void*)(aS + 64 * C_ + k0 + 32),  (void*)&As[(wave + 4) * 2 + 1][0]);
    gld16((const void*)(bS + k0),                 (void*)&Bs[wave * 2][0]);
    gld16((const void*)(bS + k0 + 32),            (void*)&Bs[wave * 2 + 1][0]);
    gld16((const void*)(bS + 64 * C_ + k0),       (void*)&Bs[(wave + 4) * 2][0]);
    gld16((const void*)(bS + 64 * C_ + k0 + 32),  (void*)&Bs[(wave + 4) * 2 + 1][0]);
    __syncthreads();  // staging drained (vmcnt(0) at barrier)

#pragma unroll
    for (int kk = 0; kk < 2; ++kk) {
      f16x8 a[4], b[4];
#pragma unroll
      for (int mi = 0; mi < 4; ++mi)
        a[mi] = *(const f16x8*)&As[(ga + mi) * 2 + kk][lane8];
#pragma unroll
      for (int ni = 0; ni < 4; ++ni)
        b[ni] = *(const f16x8*)&Bs[(gb + ni) * 2 + kk][lane8];
      __builtin_amdgcn_s_setprio(1);
#pragma unroll
      for (int mi = 0; mi < 4; ++mi)
#pragma unroll
        for (int ni = 0; ni < 4; ++ni)
          acc[mi][ni] = __builtin_amdgcn_mfma_f32_16x16x32_f16(
              a[mi], b[ni], acc[mi][ni], 0, 0, 0);
      __builtin_amdgcn_s_setprio(0);
    }
  }

  // epilogue. D layout: col = lane&15, row = (lane>>4)*4 + r   [m89/m91]
  if (z < 2) {
    _Float16* out = (z == 0) ? qh : kh;
#pragma unroll
    for (int mi = 0; mi < 4; ++mi) {
      int mbase = m0 + wm + mi * 16 + lk * 4;
#pragma unroll
      for (int ni = 0; ni < 4; ++ni) {
        int n = n0 + wn + ni * 16 + lr;
#pragma unroll
        for (int rr = 0; rr < 4; ++rr)
          out[(size_t)(mbase + rr) * H_ + n] = (_Float16)acc[mi][ni][rr];
      }
    }
  } else {
    // v^T[b][h][t]; r=0..3 are consecutive t -> pack 8B store
#pragma unroll
    for (int mi = 0; mi < 4; ++mi) {
      int mbase = m0 + wm + mi * 16 + lk * 4;
      int bb = mbase >> 8, tt = mbase & 255;
#pragma unroll
      for (int ni = 0; ni < 4; ++ni) {
        int n = n0 + wn + ni * 16 + lr;
        f16x4 u = {(_Float16)acc[mi][ni][0], (_Float16)acc[mi][ni][1],
                   (_Float16)acc[mi][ni][2], (_Float16)acc[mi][ni][3]};
        *(f16x4*)&vth[(size_t)bb * (H_ * T_) + (size_t)n * T_ + tt] = u;
      }
    }
  }
}

// ---------------------------------------------------------------- attention
// (FROZEN R12: pipelined swapped-QK^T, vf+kf early-issue, (256,2).)
__global__ __launch_bounds__(256, 2) void attn_kernel(
    const _Float16* __restrict__ qh, const _Float16* __restrict__ kh,
    const _Float16* __restrict__ vth, float* __restrict__ dout) {
  __shared__ f32x4 Ex[2][4][4][64];  // [buf][wave][chunk][lane] = 32 KB

  const int tid  = threadIdx.x;
  const int lane = tid & 63;
  const int wq   = tid >> 6;          // 0..3 = H-quarter
  const int lq   = lane & 31;         // this lane's q row (within tile)
  const int hi   = lane >> 5;
  const int flat = blockIdx.x;        // 0..1023
  const int xcd  = flat & 7;
  const int rest = flat >> 3;
  const int qb   = 7 - (rest & 7);    // long-first within each XCD stream
  const int g    = rest >> 3;         // 0..15
  const int b    = xcd + (g << 3);    // batch, pinned to XCD b%8
  const int q0   = qb * 32;
  const int nkv  = qb + 1;            // kv tiles of 32
  const int hbase = wq * 128;
  const int qg   = q0 + lq;           // global q row for this lane

  // Q as B-operand frags: lane holds Q[qg][hbase + ks*16 + hi*8 + j]
  f16x8 qf[8];
  const _Float16* qp = qh + ((size_t)b * T_ + qg) * H_ + hbase + hi * 8;
#pragma unroll
  for (int ks = 0; ks < 8; ++ks) qf[ks] = *(const f16x8*)&qp[ks * 16];

  f32x16 ot[4];  // O^T quarter
#pragma unroll
  for (int i = 0; i < 4; ++i) ot[i] = {};
  float m_ = -1e30f, l_ = 0.f;

  const _Float16* kp = kh  + ((size_t)b * T_ + lq) * H_ + hbase + hi * 8;
  const _Float16* vp = vth + ((size_t)b * H_ + hbase + lq) * T_ + hi * 8;

  // ---- prologue: QK^T(0) partial -> Ex[0]
  f16x8 kf[8], vf[8];
#pragma unroll
  for (int ks = 0; ks < 8; ++ks) kf[ks] = *(const f16x8*)&kp[ks * 16];
  {
    f32x16 s2 = {};
#pragma unroll
    for (int ks = 0; ks < 8; ++ks)
      s2 = __builtin_amdgcn_mfma_f32_32x32x16_f16(kf[ks], qf[ks], s2, 0, 0, 0);
#pragma unroll
    for (int c = 0; c < 4; ++c) {
      f32x4 w4 = {s2[c*4+0], s2[c*4+1], s2[c*4+2], s2[c*4+3]};
      Ex[0][wq][c][lane] = w4;
    }
  }

  for (int kvt = 0; kvt < nkv; ++kvt) {
    const int kv0 = kvt * 32;
    const int buf = kvt & 1;
    const bool more = (kvt + 1 < nkv);
    __syncthreads();  // Ex[buf] complete; prior reads of Ex[buf^1] done

    // ---- sum all 4 partials (16B/lane contiguous reads, conflict-free)
    f32x16 st;
#pragma unroll
    for (int c = 0; c < 4; ++c) {
      f32x4 r0 = Ex[buf][0][c][lane];
      f32x4 r1 = Ex[buf][1][c][lane];
      f32x4 r2 = Ex[buf][2][c][lane];
      f32x4 r3 = Ex[buf][3][c][lane];
      f32x4 r = (r0 + r1) + (r2 + r3);
      st[c*4+0] = r[0]; st[c*4+1] = r[1]; st[c*4+2] = r[2]; st[c*4+3] = r[3];
    }

    // ---- early-issue: V(t) for PV, K(t+1) for the back-edge QK
#pragma unroll
    for (int ht = 0; ht < 4; ++ht) {
      vf[2*ht]   = *(const f16x8*)&vp[(size_t)(ht * 32) * T_ + kv0];
      vf[2*ht+1] = *(const f16x8*)&vp[(size_t)(ht * 32) * T_ + kv0 + 16];
    }
    if (more) {
#pragma unroll
      for (int ks = 0; ks < 8; ++ks)
        kf[ks] = *(const f16x8*)&kp[(size_t)(kv0 + 32) * H_ + ks * 16];
    }

    // ---- causal mask + in-register softmax (q = lane-local), in place
    float rm = -1e30f;
    const int kvb = kv0 + 4 * hi;
#pragma unroll
    for (int r = 0; r < 16; ++r) {
      int kvg = kvb + (r & 3) + 8 * (r >> 2);
      float v = (kvg > qg) ? -1e30f : st[r];
      st[r] = v;
      rm = fmaxf(rm, v);
    }
    rm = fmaxf(rm, __shfl_xor(rm, 32, 64));

    // defer-max (T13): rescale only when max grew > 64 raw (~e^4 headroom)
    if (__any((int)(rm > m_ + 64.f))) {
      float mn = fmaxf(m_, rm);
      float al = __builtin_amdgcn_exp2f((m_ - mn) * CSCALE);
      m_ = mn; l_ *= al;
#pragma unroll
      for (int i = 0; i < 4; ++i)
#pragma unroll
        for (int e = 0; e < 16; ++e) ot[i][e] *= al;
    }
    float rs = 0.f;
#pragma unroll
    for (int r = 0; r < 16; ++r) {
      st[r] = __builtin_amdgcn_exp2f((st[r] - m_) * CSCALE);
      rs += st[r];
    }
    rs += __shfl_xor(rs, 32, 64);
    l_ += rs;

    // ---- P -> f16 pack + partner exchange -> PV B-frags
    f16x8 pb0, pb1;
    {
      f16x2 h0 = {(_Float16)st[0], (_Float16)st[1]};
      f16x2 h1 = {(_Float16)st[2], (_Float16)st[3]};
      f16x2 h2 = {(_Float16)st[4], (_Float16)st[5]};
      f16x2 h3 = {(_Float16)st[6], (_Float16)st[7]};
      u32 w0 = __builtin_bit_cast(u32, h0), w1 = __builtin_bit_cast(u32, h1);
      u32 w2 = __builtin_bit_cast(u32, h2), w3 = __builtin_bit_cast(u32, h3);
      u32 s0 = (u32)__shfl_xor((int)w0, 32, 64);
      u32 s1 = (u32)__shfl_xor((int)w1, 32, 64);
      u32 s2 = (u32)__shfl_xor((int)w2, 32, 64);
      u32 s3 = (u32)__shfl_xor((int)w3, 32, 64);
      u32x4 t0 = { hi ? s2 : w0, hi ? s3 : w1, hi ? w2 : s0, hi ? w3 : s1 };
      pb0 = __builtin_bit_cast(f16x8, t0);
    }
    {
      f16x2 h0 = {(_Float16)st[8],  (_Float16)st[9]};
      f16x2 h1 = {(_Float16)st[10], (_Float16)st[11]};
      f16x2 h2 = {(_Float16)st[12], (_Float16)st[13]};
      f16x2 h3 = {(_Float16)st[14], (_Float16)st[15]};
      u32 w0 = __builtin_bit_cast(u32, h0), w1 = __builtin_bit_cast(u32, h1);
      u32 w2 = __builtin_bit_cast(u32, h2), w3 = __builtin_bit_cast(u32, h3);
      u32 s0 = (u32)__shfl_xor((int)w0, 32, 64);
      u32 s1 = (u32)__shfl_xor((int)w1, 32, 64);
      u32 s2 = (u32)__shfl_xor((int)w2, 32, 64);
      u32 s3 = (u32)__shfl_xor((int)w3, 32, 64);
      u32x4 t1 = { hi ? s2 : w0, hi ? s3 : w1, hi ? w2 : s0, hi ? w3 : s1 };
      pb1 = __builtin_bit_cast(f16x8, t1);
    }

    // ---- PV on H-quarter (pure-register: vf prefetched)
    __builtin_amdgcn_s_setprio(1);
#pragma unroll
    for (int ht = 0; ht < 4; ++ht) {
      ot[ht] = __builtin_amdgcn_mfma_f32_32x32x16_f16(vf[2*ht],   pb0, ot[ht], 0, 0, 0);
      ot[ht] = __builtin_amdgcn_mfma_f32_32x32x16_f16(vf[2*ht+1], pb1, ot[ht], 0, 0, 0);
    }
    __builtin_amdgcn_s_setprio(0);

    // ---- QK^T(t+1) + Ex-write (pure-register: kf prefetched)
    if (more) {
      f32x16 s2v = {};
      __builtin_amdgcn_s_setprio(1);
#pragma unroll
      for (int ks = 0; ks < 8; ++ks)
        s2v = __builtin_amdgcn_mfma_f32_32x32x16_f16(kf[ks], qf[ks], s2v, 0, 0, 0);
      __builtin_amdgcn_s_setprio(0);
#pragma unroll
      for (int c = 0; c < 4; ++c) {
        f32x4 w4 = {s2v[c*4+0], s2v[c*4+1], s2v[c*4+2], s2v[c*4+3]};
        Ex[buf ^ 1][wq][c][lane] = w4;
      }
    }
  }

  // ---- normalize + store fp32 (lane's q row, wave's 128 H-cols)
  float li = 1.0f / l_;
  float* op = dout + ((size_t)b * T_ + qg) * H_ + hbase + 4 * hi;
#pragma unroll
  for (int ht = 0; ht < 4; ++ht)
#pragma unroll
    for (int rq = 0; rq < 4; ++rq) {
      f32x4 v4 = {ot[ht][rq*4+0] * li, ot[ht][rq*4+1] * li,
                  ot[ht][rq*4+2] * li, ot[ht][rq*4+3] * li};
      *(f32x4*)&op[ht * 32 + rq * 8] = v4;
    }
}

// ---------------------------------------------------------------- launch
extern "C" void kernel_launch(void* const* d_in, const int* in_sizes, int n_in,
                              void* d_out, int out_size, void* d_ws, size_t ws_size,
                              hipStream_t stream) {
  const size_t NXE = (size_t)B_ * T_ * C_;   // 16,777,216
  const size_t NWE = (size_t)3 * H_ * C_;    // 786,432
  const size_t NQE = (size_t)B_ * T_ * H_;   // 16,777,216
  const size_t need = (NXE + NWE + 3 * NQE) * sizeof(_Float16);  // 135,790,592 B
  if (ws_size < need) return;  // loud failure (absmax = max|ref|) -> ws too small

  const float* x  = (const float*)d_in[0];
  const float* wq = (const float*)d_in[1];
  const float* wk = (const float*)d_in[2];
  const float* wv = (const float*)d_in[3];

  _Float16* xh  = (_Float16*)d_ws;
  _Float16* whh = xh + NXE;
  _Float16* qh  = whh + NWE;
  _Float16* kh  = qh + NQE;
  _Float16* vth = kh + NQE;

  cvtx_kernel<<<2048, 256, 0, stream>>>((const float4*)x, (f16x4*)xh);
  cvtw_kernel<<<768, 256, 0, stream>>>((const float4*)wq, (const float4*)wk,
                                       (const float4*)wv, (f16x4*)whh);
  proj_kernel<<<3072, 256, 0, stream>>>(xh, whh, qh, kh, vth);
  attn_kernel<<<1024, 256, 0, stream>>>(qh, kh, vth, (float*)d_out);
}

// Round 14
// 171.705 us; speedup vs baseline: 1.1711x; 1.1711x over previous
//
#include <hip/hip_runtime.h>

#define B_ 128
#define T_ 256
#define C_ 512
#define H_ 512
// softmax scale * log2(e):  (1/sqrt(512)) * 1.44269504
#define CSCALE 0.063763824f

typedef _Float16 f16x8 __attribute__((ext_vector_type(8)));
typedef _Float16 f16x4 __attribute__((ext_vector_type(4)));
typedef _Float16 f16x2 __attribute__((ext_vector_type(2)));
typedef float    f32x4 __attribute__((ext_vector_type(4)));
typedef float    f32x16 __attribute__((ext_vector_type(16)));
typedef unsigned int u32;
typedef u32 u32x4 __attribute__((ext_vector_type(4)));

// async global->LDS, 16B per lane; LDS dest must be wave-uniform base (+lane*16)
__device__ __forceinline__ void gld16(const void* gsrc, void* ldst) {
  __builtin_amdgcn_global_load_lds(
      (__attribute__((address_space(1))) void*)gsrc,
      (__attribute__((address_space(3))) void*)ldst, 16, 0, 0);
}

// ---------------------------------------------------------------- x convert
__global__ __launch_bounds__(256) void cvtx_kernel(
    const float4* __restrict__ x, f16x4* __restrict__ dst) {
  const int NX = (B_ * T_ * C_) / 4;  // 4,194,304
  int gid = blockIdx.x * 256 + threadIdx.x;
  int gsz = gridDim.x * 256;
  for (int i = gid; i < NX; i += gsz) {
    float4 f = x[i];
    f16x4 u = {(_Float16)f.x, (_Float16)f.y, (_Float16)f.z, (_Float16)f.w};
    dst[i] = u;
  }
}

// ---------------------------------------------------------------- W convert
__global__ __launch_bounds__(256) void cvtw_kernel(
    const float4* __restrict__ wq, const float4* __restrict__ wk,
    const float4* __restrict__ wv, f16x4* __restrict__ dst) {
  const int NW = (H_ * C_) / 4;  // 65,536
  int i = blockIdx.x * 256 + threadIdx.x;
  if (i >= 3 * NW) return;
  float4 f = (i < NW) ? wq[i] : (i < 2 * NW ? wk[i - NW] : wv[i - 2 * NW]);
  f16x4 u = {(_Float16)f.x, (_Float16)f.y, (_Float16)f.z, (_Float16)f.w};
  dst[i] = u;
}

// ---------------------------------------------------------------- QKV proj
// (RESTORED R5-EXACT -- R13's bundle (XCD reorder + BK=64) cut FETCH 72->27MB
// but cost +37us => proj is NOT fetch-limited; unbundled per plan.
// Scoreboard: R5 2-barrier 80 / 8-phase 80 / ring 115 / z-merge 101 /
// fused-fp32 170 / locality+BK64 117. 80 us is this shape's floor.)
__global__ __launch_bounds__(256) void proj_kernel(
    const _Float16* __restrict__ xh, const _Float16* __restrict__ wh,
    _Float16* __restrict__ qh, _Float16* __restrict__ kh,
    _Float16* __restrict__ vth) {
  __shared__ _Float16 As[128 * 32];  // 8 KB, row-major [128][32]
  __shared__ _Float16 Bs[128 * 32];  // 8 KB

  const int tid  = threadIdx.x;
  const int lane = tid & 63;
  const int wave = tid >> 6;
  const int lr = lane & 15, lk = lane >> 4;
  const int m0 = blockIdx.x * 128;
  const int n0 = blockIdx.y * 128;
  const int z  = blockIdx.z;
  const _Float16* wz = wh + z * (H_ * C_);

  const int wm = (wave >> 1) * 64;
  const int wn = (wave & 1) * 64;

  f32x4 acc[4][4];
#pragma unroll
  for (int i = 0; i < 4; ++i)
#pragma unroll
    for (int j = 0; j < 4; ++j) acc[i][j] = {0.f, 0.f, 0.f, 0.f};

  const int srow = tid >> 2, scol = (tid & 3) * 8;
  const _Float16* aSrc = xh + (size_t)(m0 + srow) * C_ + scol;
  const _Float16* bSrc = wz + (size_t)(n0 + srow) * C_ + scol;

  for (int k0 = 0; k0 < C_; k0 += 32) {
    __syncthreads();
#pragma unroll
    for (int i = 0; i < 2; ++i) {
      gld16((const void*)(aSrc + i * 64 * C_ + k0), (void*)&As[i * 2048 + wave * 512]);
      gld16((const void*)(bSrc + i * 64 * C_ + k0), (void*)&Bs[i * 2048 + wave * 512]);
    }
    __syncthreads();

    f16x8 a[4], b[4];
#pragma unroll
    for (int mi = 0; mi < 4; ++mi)
      a[mi] = *(const f16x8*)&As[(wm + mi * 16 + lr) * 32 + lk * 8];
#pragma unroll
    for (int ni = 0; ni < 4; ++ni)
      b[ni] = *(const f16x8*)&Bs[(wn + ni * 16 + lr) * 32 + lk * 8];
#pragma unroll
    for (int mi = 0; mi < 4; ++mi)
#pragma unroll
      for (int ni = 0; ni < 4; ++ni)
        acc[mi][ni] = __builtin_amdgcn_mfma_f32_16x16x32_f16(a[mi], b[ni], acc[mi][ni], 0, 0, 0);
  }

  if (z < 2) {
    _Float16* out = (z == 0) ? qh : kh;
#pragma unroll
    for (int mi = 0; mi < 4; ++mi) {
      int mbase = m0 + wm + mi * 16 + lk * 4;
#pragma unroll
      for (int ni = 0; ni < 4; ++ni) {
        int n = n0 + wn + ni * 16 + lr;
#pragma unroll
        for (int r = 0; r < 4; ++r)
          out[(size_t)(mbase + r) * H_ + n] = (_Float16)acc[mi][ni][r];
      }
    }
  } else {
#pragma unroll
    for (int mi = 0; mi < 4; ++mi) {
      int mbase = m0 + wm + mi * 16 + lk * 4;
      int bb = mbase >> 8, tt = mbase & 255;
#pragma unroll
      for (int ni = 0; ni < 4; ++ni) {
        int n = n0 + wn + ni * 16 + lr;
        f16x4 u = {(_Float16)acc[mi][ni][0], (_Float16)acc[mi][ni][1],
                   (_Float16)acc[mi][ni][2], (_Float16)acc[mi][ni][3]};
        *(f16x4*)&vth[(size_t)bb * (H_ * T_) + (size_t)n * T_ + tt] = u;
      }
    }
  }
}

// ---------------------------------------------------------------- attention
// R12 structure + ANTI-SINK FENCE: __builtin_amdgcn_sched_barrier(0) right
// after the early-issue vf/kf loads. Theory: hipcc's scheduler sinks
// register loads to first use (register-pressure heuristic), silently
// turning R8/R11/R12's "early issue" into load-at-use -- explaining why all
// three variants measured the same ~84us with a 10x gap vs the ~500-800cy
// per-tile arithmetic. The fence pins the load issue point; the auto
// s_waitcnt before first use stays late -> softmax+pack covers the latency.
// Compile-time only: worst case neutral.
__global__ __launch_bounds__(256, 2) void attn_kernel(
    const _Float16* __restrict__ qh, const _Float16* __restrict__ kh,
    const _Float16* __restrict__ vth, float* __restrict__ dout) {
  __shared__ f32x4 Ex[2][4][4][64];  // [buf][wave][chunk][lane] = 32 KB

  const int tid  = threadIdx.x;
  const int lane = tid & 63;
  const int wq   = tid >> 6;          // 0..3 = H-quarter
  const int lq   = lane & 31;         // this lane's q row (within tile)
  const int hi   = lane >> 5;
  const int flat = blockIdx.x;        // 0..1023
  const int xcd  = flat & 7;
  const int rest = flat >> 3;
  const int qb   = 7 - (rest & 7);    // long-first within each XCD stream
  const int g    = rest >> 3;         // 0..15
  const int b    = xcd + (g << 3);    // batch, pinned to XCD b%8
  const int q0   = qb * 32;
  const int nkv  = qb + 1;            // kv tiles of 32
  const int hbase = wq * 128;
  const int qg   = q0 + lq;           // global q row for this lane

  // Q as B-operand frags: lane holds Q[qg][hbase + ks*16 + hi*8 + j]
  f16x8 qf[8];
  const _Float16* qp = qh + ((size_t)b * T_ + qg) * H_ + hbase + hi * 8;
#pragma unroll
  for (int ks = 0; ks < 8; ++ks) qf[ks] = *(const f16x8*)&qp[ks * 16];

  f32x16 ot[4];  // O^T quarter
#pragma unroll
  for (int i = 0; i < 4; ++i) ot[i] = {};
  float m_ = -1e30f, l_ = 0.f;

  const _Float16* kp = kh  + ((size_t)b * T_ + lq) * H_ + hbase + hi * 8;
  const _Float16* vp = vth + ((size_t)b * H_ + hbase + lq) * T_ + hi * 8;

  // ---- prologue: QK^T(0) partial -> Ex[0]
  f16x8 kf[8], vf[8];
#pragma unroll
  for (int ks = 0; ks < 8; ++ks) kf[ks] = *(const f16x8*)&kp[ks * 16];
  {
    f32x16 s2 = {};
#pragma unroll
    for (int ks = 0; ks < 8; ++ks)
      s2 = __builtin_amdgcn_mfma_f32_32x32x16_f16(kf[ks], qf[ks], s2, 0, 0, 0);
#pragma unroll
    for (int c = 0; c < 4; ++c) {
      f32x4 w4 = {s2[c*4+0], s2[c*4+1], s2[c*4+2], s2[c*4+3]};
      Ex[0][wq][c][lane] = w4;
    }
  }

  for (int kvt = 0; kvt < nkv; ++kvt) {
    const int kv0 = kvt * 32;
    const int buf = kvt & 1;
    const bool more = (kvt + 1 < nkv);
    __syncthreads();  // Ex[buf] complete; prior reads of Ex[buf^1] done

    // ---- sum all 4 partials (16B/lane contiguous reads, conflict-free)
    f32x16 st;
#pragma unroll
    for (int c = 0; c < 4; ++c) {
      f32x4 r0 = Ex[buf][0][c][lane];
      f32x4 r1 = Ex[buf][1][c][lane];
      f32x4 r2 = Ex[buf][2][c][lane];
      f32x4 r3 = Ex[buf][3][c][lane];
      f32x4 r = (r0 + r1) + (r2 + r3);
      st[c*4+0] = r[0]; st[c*4+1] = r[1]; st[c*4+2] = r[2]; st[c*4+3] = r[3];
    }

    // ---- early-issue: V(t) for PV, K(t+1) for the back-edge QK
#pragma unroll
    for (int ht = 0; ht < 4; ++ht) {
      vf[2*ht]   = *(const f16x8*)&vp[(size_t)(ht * 32) * T_ + kv0];
      vf[2*ht+1] = *(const f16x8*)&vp[(size_t)(ht * 32) * T_ + kv0 + 16];
    }
    if (more) {
#pragma unroll
      for (int ks = 0; ks < 8; ++ks)
        kf[ks] = *(const f16x8*)&kp[(size_t)(kv0 + 32) * H_ + ks * 16];
    }
    // ANTI-SINK: loads may not be scheduled below this point; their
    // s_waitcnt stays at first use (PV / QK-next) -> latency hides under
    // the softmax+pack VALU block.
    __builtin_amdgcn_sched_barrier(0);

    // ---- causal mask + in-register softmax (q = lane-local), in place
    float rm = -1e30f;
    const int kvb = kv0 + 4 * hi;
#pragma unroll
    for (int r = 0; r < 16; ++r) {
      int kvg = kvb + (r & 3) + 8 * (r >> 2);
      float v = (kvg > qg) ? -1e30f : st[r];
      st[r] = v;
      rm = fmaxf(rm, v);
    }
    rm = fmaxf(rm, __shfl_xor(rm, 32, 64));

    // defer-max (T13): rescale only when max grew > 64 raw (~e^4 headroom)
    if (__any((int)(rm > m_ + 64.f))) {
      float mn = fmaxf(m_, rm);
      float al = __builtin_amdgcn_exp2f((m_ - mn) * CSCALE);
      m_ = mn; l_ *= al;
#pragma unroll
      for (int i = 0; i < 4; ++i)
#pragma unroll
        for (int e = 0; e < 16; ++e) ot[i][e] *= al;
    }
    float rs = 0.f;
#pragma unroll
    for (int r = 0; r < 16; ++r) {
      st[r] = __builtin_amdgcn_exp2f((st[r] - m_) * CSCALE);
      rs += st[r];
    }
    rs += __shfl_xor(rs, 32, 64);
    l_ += rs;

    // ---- P -> f16 pack + partner exchange -> PV B-frags
    f16x8 pb0, pb1;
    {
      f16x2 h0 = {(_Float16)st[0], (_Float16)st[1]};
      f16x2 h1 = {(_Float16)st[2], (_Float16)st[3]};
      f16x2 h2 = {(_Float16)st[4], (_Float16)st[5]};
      f16x2 h3 = {(_Float16)st[6], (_Float16)st[7]};
      u32 w0 = __builtin_bit_cast(u32, h0), w1 = __builtin_bit_cast(u32, h1);
      u32 w2 = __builtin_bit_cast(u32, h2), w3 = __builtin_bit_cast(u32, h3);
      u32 s0 = (u32)__shfl_xor((int)w0, 32, 64);
      u32 s1 = (u32)__shfl_xor((int)w1, 32, 64);
      u32 s2 = (u32)__shfl_xor((int)w2, 32, 64);
      u32 s3 = (u32)__shfl_xor((int)w3, 32, 64);
      u32x4 t0 = { hi ? s2 : w0, hi ? s3 : w1, hi ? w2 : s0, hi ? w3 : s1 };
      pb0 = __builtin_bit_cast(f16x8, t0);
    }
    {
      f16x2 h0 = {(_Float16)st[8],  (_Float16)st[9]};
      f16x2 h1 = {(_Float16)st[10], (_Float16)st[11]};
      f16x2 h2 = {(_Float16)st[12], (_Float16)st[13]};
      f16x2 h3 = {(_Float16)st[14], (_Float16)st[15]};
      u32 w0 = __builtin_bit_cast(u32, h0), w1 = __builtin_bit_cast(u32, h1);
      u32 w2 = __builtin_bit_cast(u32, h2), w3 = __builtin_bit_cast(u32, h3);
      u32 s0 = (u32)__shfl_xor((int)w0, 32, 64);
      u32 s1 = (u32)__shfl_xor((int)w1, 32, 64);
      u32 s2 = (u32)__shfl_xor((int)w2, 32, 64);
      u32 s3 = (u32)__shfl_xor((int)w3, 32, 64);
      u32x4 t1 = { hi ? s2 : w0, hi ? s3 : w1, hi ? w2 : s0, hi ? w3 : s1 };
      pb1 = __builtin_bit_cast(f16x8, t1);
    }

    // ---- PV on H-quarter (vf issued at tile top)
    __builtin_amdgcn_s_setprio(1);
#pragma unroll
    for (int ht = 0; ht < 4; ++ht) {
      ot[ht] = __builtin_amdgcn_mfma_f32_32x32x16_f16(vf[2*ht],   pb0, ot[ht], 0, 0, 0);
      ot[ht] = __builtin_amdgcn_mfma_f32_32x32x16_f16(vf[2*ht+1], pb1, ot[ht], 0, 0, 0);
    }
    __builtin_amdgcn_s_setprio(0);

    // ---- QK^T(t+1) + Ex-write (kf issued at tile top)
    if (more) {
      f32x16 s2v = {};
      __builtin_amdgcn_s_setprio(1);
#pragma unroll
      for (int ks = 0; ks < 8; ++ks)
        s2v = __builtin_amdgcn_mfma_f32_32x32x16_f16(kf[ks], qf[ks], s2v, 0, 0, 0);
      __builtin_amdgcn_s_setprio(0);
#pragma unroll
      for (int c = 0; c < 4; ++c) {
        f32x4 w4 = {s2v[c*4+0], s2v[c*4+1], s2v[c*4+2], s2v[c*4+3]};
        Ex[buf ^ 1][wq][c][lane] = w4;
      }
    }
  }

  // ---- normalize + store fp32 (lane's q row, wave's 128 H-cols)
  float li = 1.0f / l_;
  float* op = dout + ((size_t)b * T_ + qg) * H_ + hbase + 4 * hi;
#pragma unroll
  for (int ht = 0; ht < 4; ++ht)
#pragma unroll
    for (int rq = 0; rq < 4; ++rq) {
      f32x4 v4 = {ot[ht][rq*4+0] * li, ot[ht][rq*4+1] * li,
                  ot[ht][rq*4+2] * li, ot[ht][rq*4+3] * li};
      *(f32x4*)&op[ht * 32 + rq * 8] = v4;
    }
}

// ---------------------------------------------------------------- launch
extern "C" void kernel_launch(void* const* d_in, const int* in_sizes, int n_in,
                              void* d_out, int out_size, void* d_ws, size_t ws_size,
                              hipStream_t stream) {
  const size_t NXE = (size_t)B_ * T_ * C_;   // 16,777,216
  const size_t NWE = (size_t)3 * H_ * C_;    // 786,432
  const size_t NQE = (size_t)B_ * T_ * H_;   // 16,777,216
  const size_t need = (NXE + NWE + 3 * NQE) * sizeof(_Float16);  // 135,790,592 B
  if (ws_size < need) return;  // loud failure (absmax = max|ref|) -> ws too small

  const float* x  = (const float*)d_in[0];
  const float* wq = (const float*)d_in[1];
  const float* wk = (const float*)d_in[2];
  const float* wv = (const float*)d_in[3];

  _Float16* xh  = (_Float16*)d_ws;
  _Float16* whh = xh + NXE;
  _Float16* qh  = whh + NWE;
  _Float16* kh  = qh + NQE;
  _Float16* vth = kh + NQE;

  cvtx_kernel<<<2048, 256, 0, stream>>>((const float4*)x, (f16x4*)xh);
  cvtw_kernel<<<768, 256, 0, stream>>>((const float4*)wq, (const float4*)wk,
                                       (const float4*)wv, (f16x4*)whh);
  proj_kernel<<<dim3(256, 4, 3), dim3(256), 0, stream>>>(xh, whh, qh, kh, vth);
  attn_kernel<<<1024, 256, 0, stream>>>(qh, kh, vth, (float*)d_out);
}